// Round 2
// baseline (307.853 us; speedup 1.0000x reference)
//
#include <hip/hip_runtime.h>
#include <stdint.h>

#define BATCH 16
#define CH    256
#define NSP   4096   // 64*64 spatial
#define NH    4
#define HD    64

typedef __attribute__((ext_vector_type(8))) short bf16x8;
typedef __attribute__((ext_vector_type(4))) float f32x4;
typedef __attribute__((ext_vector_type(4))) unsigned int u32x4;

__device__ __forceinline__ short f2bf(float f) {
    union { float f; unsigned u; } v; v.f = f;
    unsigned r = (v.u + 0x7fffu + ((v.u >> 16) & 1u)) >> 16;
    return (short)r;
}
__device__ __forceinline__ float bf2f(short s) {
    union { float f; unsigned u; } v; v.u = ((unsigned)(unsigned short)s) << 16;
    return v.f;
}

// ---------------- fused: GN stats (blocks 0..511) + weight bf16 convert (512..767) ----------------
__global__ __launch_bounds__(256) void k_pre(
        const float* __restrict__ x, const float* __restrict__ wq, const float* __restrict__ wo,
        float* __restrict__ mu, float* __restrict__ rstd,
        short* __restrict__ wq_bf, short* __restrict__ wo_bf) {
    int bg = blockIdx.x;
    if (bg < 512) {
        const float4* p = (const float4*)(x + (size_t)bg * 32768);
        float s = 0.f, sq = 0.f;
        for (int i = threadIdx.x; i < 8192; i += 256) {
            float4 v = p[i];
            s  += v.x + v.y + v.z + v.w;
            sq += v.x * v.x + v.y * v.y + v.z * v.z + v.w * v.w;
        }
        for (int off = 32; off; off >>= 1) { s += __shfl_down(s, off); sq += __shfl_down(sq, off); }
        __shared__ float ls[4], lq[4];
        int w = threadIdx.x >> 6;
        if ((threadIdx.x & 63) == 0) { ls[w] = s; lq[w] = sq; }
        __syncthreads();
        if (threadIdx.x == 0) {
            float S = ls[0] + ls[1] + ls[2] + ls[3];
            float Q = lq[0] + lq[1] + lq[2] + lq[3];
            float m = S / 32768.f;
            float var = Q / 32768.f - m * m;
            mu[bg] = m; rstd[bg] = rsqrtf(var + 1e-5f);
        }
    } else {
        int idx = ((bg - 512) * 256 + threadIdx.x) * 4;
        float4 v;
        short* dst;
        if (idx < 196608) { v = *(const float4*)(wq + idx); dst = wq_bf + idx; }
        else              { v = *(const float4*)(wo + (idx - 196608)); dst = wo_bf + (idx - 196608); }
        unsigned p0 = ((unsigned)(unsigned short)f2bf(v.x)) | (((unsigned)(unsigned short)f2bf(v.y)) << 16);
        unsigned p1 = ((unsigned)(unsigned short)f2bf(v.z)) | (((unsigned)(unsigned short)f2bf(v.w)) << 16);
        uint2 pk; pk.x = p0; pk.y = p1;
        *(uint2*)dst = pk;
    }
}

// ---------------- fused GN-apply + QKV + kv^T/ksum partials + q_t ----------------
// Grid (32,16): 2 n-tiles per block -> 512 blocks = 2/CU, all co-resident, no tail.
// A-fragments (weights) are PREFETCHED 8-deep into registers before each MFMA loop
// (16 independent global loads issue back-to-back; only one L2 latency exposed per pass).
__global__ __launch_bounds__(256) void k_gnqkv(
        const float* __restrict__ x, const float* __restrict__ gamma, const float* __restrict__ beta,
        const float* __restrict__ mu, const float* __restrict__ rstd,
        const short* __restrict__ wq_bf, const float* __restrict__ b_qkv,
        short* __restrict__ q_t, short* __restrict__ kvp_bf, float* __restrict__ ksp) {
    int b = blockIdx.y;
    __shared__ short Blds[64 * 264];          // [n][c^swz]
    __shared__ union UR {
        struct { short kst[64 * 72]; short vst[64 * 72]; } s;
        short cst[64 * 136];
    } R;
    int t = threadIdx.x, lane = t & 63, wv = t >> 6, lr = lane & 15, quad = lane >> 4;

    for (int it = 0; it < 2; it++) {
        int nt = blockIdx.x * 2 + it;
        int n0 = nt * 64;

        // ---- build B tile with GN ----
        {
            const float* xb = x + (size_t)b * CH * NSP;
            int m = t & 15, cq = t >> 4;
            #pragma unroll 4
            for (int cb = 0; cb < 16; cb++) {
                int c = cb * 16 + cq;
                int g = c >> 3;
                float sc = rstd[b * 32 + g] * gamma[c];
                float sh = beta[c] - mu[b * 32 + g] * sc;
                float4 v = *(const float4*)(xb + (size_t)c * NSP + n0 + m * 4);
                float vv[4] = {v.x, v.y, v.z, v.w};
                #pragma unroll
                for (int j = 0; j < 4; j++) {
                    int n = m * 4 + j;
                    int cc = c ^ (((n >> 4) & 3) << 3);
                    Blds[n * 264 + cc] = f2bf(vv[j] * sc + sh);
                }
            }
        }
        __syncthreads();

        // ---- per-head k/v + kv partial ----
        for (int h = 0; h < 4; h++) {
            int br0 = (wv < 2 ? 256 : 512) + h * 64;   // k rows waves 0-1, v rows waves 2-3
            int sub = (wv & 1) * 32;
            const short* wr = wq_bf + (size_t)(br0 + sub + lr) * 256 + quad * 8;
            bf16x8 A0[8], A1[8];                        // 8-deep A prefetch (issue all 16 loads now)
            #pragma unroll
            for (int kk = 0; kk < 8; kk++) {
                A0[kk] = *(const bf16x8*)(wr + kk * 32);
                A1[kk] = *(const bf16x8*)(wr + 16 * 256 + kk * 32);
            }
            f32x4 acc[2][4] = {};
            #pragma unroll
            for (int kk = 0; kk < 8; kk++) {
                bf16x8 bfr[4];
                #pragma unroll
                for (int ni = 0; ni < 4; ni++) {
                    int rr = ni * 16 + lr;
                    bfr[ni] = *(const bf16x8*)(Blds + rr * 264 + ((kk * 32 + quad * 8) ^ (((rr >> 4) & 3) << 3)));
                }
                #pragma unroll
                for (int ni = 0; ni < 4; ni++) {
                    acc[0][ni] = __builtin_amdgcn_mfma_f32_16x16x32_bf16(A0[kk], bfr[ni], acc[0][ni], 0, 0, 0);
                    acc[1][ni] = __builtin_amdgcn_mfma_f32_16x16x32_bf16(A1[kk], bfr[ni], acc[1][ni], 0, 0, 0);
                }
            }
            __syncthreads();   // protect R reuse from previous pass
            short* dst = (wv < 2) ? R.s.kst : R.s.vst;
            bool is_k = (wv < 2);
            #pragma unroll
            for (int mi = 0; mi < 2; mi++)
              #pragma unroll
              for (int ni = 0; ni < 4; ni++)
                #pragma unroll
                for (int r = 0; r < 4; r++) {
                    int ol = sub + mi * 16 + quad * 4 + r;   // 0..63
                    int nl = ni * 16 + lr;
                    float v = acc[mi][ni][r] + b_qkv[br0 + ol];
                    if (is_k) v = v > 0.f ? v + 1.f : __expf(v);   // elu(k)+1
                    dst[ol * 72 + nl] = f2bf(v);
                }
            __syncthreads();
            // ksum partial
            {
                int d = t >> 2, nq = (t & 3) * 16;
                float s = 0.f;
                #pragma unroll
                for (int j = 0; j < 16; j++) s += bf2f(R.s.kst[d * 72 + nq + j]);
                s += __shfl_down(s, 2);
                s += __shfl_down(s, 1);
                if ((t & 3) == 0) ksp[((size_t)(b * 4 + h) * 64 + nt) * 64 + d] = s;
            }
            // kv^T partial: A = vst (e rows), B = kst (d rows), K = 64 n
            f32x4 acc2[4] = {};
            #pragma unroll
            for (int kk = 0; kk < 64; kk += 32) {
                bf16x8 af = *(const bf16x8*)(R.s.vst + (wv * 16 + lr) * 72 + kk + quad * 8);
                bf16x8 bfk[4];
                #pragma unroll
                for (int ni = 0; ni < 4; ni++)
                    bfk[ni] = *(const bf16x8*)(R.s.kst + (ni * 16 + lr) * 72 + kk + quad * 8);
                #pragma unroll
                for (int ni = 0; ni < 4; ni++)
                    acc2[ni] = __builtin_amdgcn_mfma_f32_16x16x32_bf16(af, bfk[ni], acc2[ni], 0, 0, 0);
            }
            short* kvdst = kvp_bf + ((size_t)(b * 4 + h) * 64 + nt) * 4096;
            #pragma unroll
            for (int ni = 0; ni < 4; ni++)
                #pragma unroll
                for (int r = 0; r < 4; r++)
                    kvdst[(wv * 16 + quad * 4 + r) * 64 + ni * 16 + lr] = f2bf(acc2[ni][r]);
        }

        // ---- q passes (128 rows each) ----
        for (int mtq = 0; mtq < 2; mtq++) {
            int wm = wv * 32;
            const short* wr = wq_bf + (size_t)(mtq * 128 + wm + lr) * 256 + quad * 8;
            bf16x8 A0[8], A1[8];
            #pragma unroll
            for (int kk = 0; kk < 8; kk++) {
                A0[kk] = *(const bf16x8*)(wr + kk * 32);
                A1[kk] = *(const bf16x8*)(wr + 16 * 256 + kk * 32);
            }
            f32x4 acc[2][4] = {};
            #pragma unroll
            for (int kk = 0; kk < 8; kk++) {
                bf16x8 bfr[4];
                #pragma unroll
                for (int ni = 0; ni < 4; ni++) {
                    int rr = ni * 16 + lr;
                    bfr[ni] = *(const bf16x8*)(Blds + rr * 264 + ((kk * 32 + quad * 8) ^ (((rr >> 4) & 3) << 3)));
                }
                #pragma unroll
                for (int ni = 0; ni < 4; ni++) {
                    acc[0][ni] = __builtin_amdgcn_mfma_f32_16x16x32_bf16(A0[kk], bfr[ni], acc[0][ni], 0, 0, 0);
                    acc[1][ni] = __builtin_amdgcn_mfma_f32_16x16x32_bf16(A1[kk], bfr[ni], acc[1][ni], 0, 0, 0);
                }
            }
            __syncthreads();   // protect cst reuse
            #pragma unroll
            for (int mi = 0; mi < 2; mi++)
              #pragma unroll
              for (int ni = 0; ni < 4; ni++)
                #pragma unroll
                for (int r = 0; r < 4; r++) {
                    int ol = wm + mi * 16 + quad * 4 + r;    // 0..127
                    int nl = ni * 16 + lr;
                    float v = acc[mi][ni][r] + b_qkv[mtq * 128 + ol];
                    v = v > 0.f ? v + 1.f : __expf(v);       // elu(q)+1
                    R.cst[nl * 136 + ol] = f2bf(v);
                }
            __syncthreads();
            #pragma unroll
            for (int i = 0; i < 4; i++) {
                int ch = t + i * 256;
                int row = ch >> 4, o8 = (ch & 15) * 8;
                int hh = mtq * 2 + (o8 >> 6), d0 = o8 & 63;
                *(u32x4*)(q_t + ((size_t)(b * 4 + hh) * NSP + n0 + row) * HD + d0) =
                    *(const u32x4*)(R.cst + row * 136 + o8);
            }
        }
    }
}

// ---------------- reduce bf16 kv partials -> bf16 kvT; fp32 ksum ----------------
// Grid (8,64) = 512 blocks (was 128 -> 0.5/CU, latency-bound). Each block: 64 chunks,
// 4 wave-groups each reduce 16 of the 64 n-tile partials, LDS combine.
__global__ __launch_bounds__(256) void k_kv_reduce(
        const short* __restrict__ kvp_bf, const float* __restrict__ ksp,
        short* __restrict__ kvT_bf, float* __restrict__ ksum_g) {
    int p = blockIdx.x, bh = blockIdx.y;
    int t = threadIdx.x, lane = t & 63, grp = t >> 6;
    int chunk = p * 64 + lane;                 // 0..511, 8 elems each
    const short* base = kvp_bf + (size_t)bh * 64 * 4096 + chunk * 8;
    float s[8] = {};
    for (int ntc = grp * 16; ntc < grp * 16 + 16; ntc++) {
        bf16x8 v = *(const bf16x8*)(base + (size_t)ntc * 4096);
        #pragma unroll
        for (int j = 0; j < 8; j++) s[j] += bf2f(v[j]);
    }
    __shared__ float red[4][64][8];
    if (grp) {
        #pragma unroll
        for (int j = 0; j < 8; j++) red[grp][lane][j] = s[j];
    }
    __syncthreads();
    if (grp == 0) {
        bf16x8 rv;
        #pragma unroll
        for (int j = 0; j < 8; j++) {
            float v = s[j] + red[1][lane][j] + red[2][lane][j] + red[3][lane][j];
            rv[j] = f2bf(v);
        }
        *(bf16x8*)(kvT_bf + (size_t)bh * 4096 + chunk * 8) = rv;
    }
    if (p == 0) {   // block-uniform branch
        const float* kb = ksp + (size_t)bh * 64 * 64 + lane;
        float ss = 0.f;
        for (int ntc = grp * 16; ntc < grp * 16 + 16; ntc++) ss += kb[(size_t)ntc * 64];
        __syncthreads();
        red[grp][lane][0] = ss;
        __syncthreads();
        if (grp == 0) ksum_g[bh * 64 + lane] = ss + red[1][lane][0] + red[2][lane][0] + red[3][lane][0];
    }
}

// ---------------- fused attention + out-projection + residual ----------------
// Restructured: q_t [n][d] and kvT [e][d] are ALREADY in MFMA fragment layout in global
// (16B/lane contiguous, L2-resident) -> no ql/kvl LDS staging. All 4 heads' denominators
// precomputed in one parallel pass (one thread per (h,n)). 2 barriers per tile (was ~13).
// Grid (32,16): 2 tiles/block, uniform residency. wo A-fragments prefetched 8-deep.
__global__ __launch_bounds__(256) void k_attn_out(
        const short* __restrict__ q_t, const short* __restrict__ kvT_bf,
        const float* __restrict__ ksum_g, const short* __restrict__ wo_bf,
        const float* __restrict__ b_out, const float* __restrict__ x,
        float* __restrict__ out) {
    int b = blockIdx.y;
    __shared__ short Battn[64 * 264];
    __shared__ float dnl[4][64];
    int t = threadIdx.x, lane = t & 63, wv = t >> 6, lr = lane & 15, quad = lane >> 4;

    for (int it = 0; it < 2; it++) {
        int nt = blockIdx.x * 2 + it;
        int n0 = nt * 64;

        // denom precompute: thread (h=wv, n=lane), fully parallel (256 = 4h x 64n)
        {
            const short* qp = q_t + ((size_t)(b * 4 + wv) * NSP + n0 + lane) * HD;
            const float* ks = ksum_g + (b * 4 + wv) * 64;
            float s = 0.f;
            #pragma unroll
            for (int c8 = 0; c8 < 8; c8++) {
                bf16x8 qv = *(const bf16x8*)(qp + c8 * 8);
                #pragma unroll
                for (int j = 0; j < 8; j++) s += bf2f(qv[j]) * ks[c8 * 8 + j];
            }
            dnl[wv][lane] = 1.f / (s + 1e-6f);
        }
        __syncthreads();

        // per-head attention, operands direct from global (barrier-free)
        for (int h = 0; h < 4; h++) {
            size_t bh = (size_t)(b * 4 + h);
            const short* qbase = q_t + (bh * NSP + n0) * HD;
            const short* kvbase = kvT_bf + bh * 4096;
            bf16x8 af[2], bfr[2][4];
            #pragma unroll
            for (int kz = 0; kz < 2; kz++) {
                af[kz] = *(const bf16x8*)(qbase + (wv * 16 + lr) * HD + kz * 32 + quad * 8);
                #pragma unroll
                for (int ni = 0; ni < 4; ni++)
                    bfr[kz][ni] = *(const bf16x8*)(kvbase + (ni * 16 + lr) * HD + kz * 32 + quad * 8);
            }
            f32x4 acc[4] = {};
            #pragma unroll
            for (int kz = 0; kz < 2; kz++)
                #pragma unroll
                for (int ni = 0; ni < 4; ni++)
                    acc[ni] = __builtin_amdgcn_mfma_f32_16x16x32_bf16(af[kz], bfr[kz][ni], acc[ni], 0, 0, 0);
            #pragma unroll
            for (int ni = 0; ni < 4; ni++)
                #pragma unroll
                for (int r = 0; r < 4; r++) {
                    int n = wv * 16 + quad * 4 + r;
                    Battn[n * 264 + h * 64 + ni * 16 + lr] = f2bf(acc[ni][r] * dnl[h][n]);
                }
        }
        __syncthreads();

        // out GEMM: 2 passes of 128 o, A prefetched 8-deep
        for (int p = 0; p < 2; p++) {
            int rbase = p * 128 + wv * 32;
            const short* wr = wo_bf + (size_t)(rbase + lr) * 256 + quad * 8;
            bf16x8 A0[8], A1[8];
            #pragma unroll
            for (int kk = 0; kk < 8; kk++) {
                A0[kk] = *(const bf16x8*)(wr + kk * 32);
                A1[kk] = *(const bf16x8*)(wr + 16 * 256 + kk * 32);
            }
            f32x4 acc[2][4] = {};
            #pragma unroll
            for (int kk = 0; kk < 8; kk++) {
                bf16x8 bfr[4];
                #pragma unroll
                for (int ni = 0; ni < 4; ni++)
                    bfr[ni] = *(const bf16x8*)(Battn + (ni * 16 + lr) * 264 + kk * 32 + quad * 8);
                #pragma unroll
                for (int ni = 0; ni < 4; ni++) {
                    acc[0][ni] = __builtin_amdgcn_mfma_f32_16x16x32_bf16(A0[kk], bfr[ni], acc[0][ni], 0, 0, 0);
                    acc[1][ni] = __builtin_amdgcn_mfma_f32_16x16x32_bf16(A1[kk], bfr[ni], acc[1][ni], 0, 0, 0);
                }
            }
            #pragma unroll
            for (int mi = 0; mi < 2; mi++)
              #pragma unroll
              for (int ni = 0; ni < 4; ni++)
                #pragma unroll
                for (int r = 0; r < 4; r++) {
                    int o = rbase + mi * 16 + quad * 4 + r;
                    int nl = ni * 16 + lr;
                    size_t idx = ((size_t)b * CH + o) * NSP + n0 + nl;
                    out[idx] = acc[mi][ni][r] + b_out[o] + x[idx];
                }
        }
        // next tile's post-denom barrier protects Battn/dnl reuse (all waves must
        // finish this tile's out-GEMM reads before reaching it)
    }
}

extern "C" void kernel_launch(void* const* d_in, const int* in_sizes, int n_in,
                              void* d_out, int out_size, void* d_ws, size_t ws_size,
                              hipStream_t stream) {
    const float* x     = (const float*)d_in[0];
    const float* gamma = (const float*)d_in[1];
    const float* beta  = (const float*)d_in[2];
    const float* w_qkv = (const float*)d_in[3];
    const float* b_qkv = (const float*)d_in[4];
    const float* w_out = (const float*)d_in[5];
    const float* b_out = (const float*)d_in[6];
    float* out = (float*)d_out;

    char* ws = (char*)d_ws;
    size_t off = 0;
    float* mu     = (float*)(ws + off); off += 2048;
    float* rstd   = (float*)(ws + off); off += 2048;
    short* wq_bf  = (short*)(ws + off); off += (size_t)768 * 256 * 2;
    short* wo_bf  = (short*)(ws + off); off += (size_t)256 * 256 * 2;
    short* q_t    = (short*)(ws + off); off += (size_t)BATCH * NSP * CH * 2;   // [b][h][n][d]
    short* kvp_bf = (short*)(ws + off); off += (size_t)64 * 64 * 4096 * 2;     // [bh][nt64][e][d] bf16
    float* ksp    = (float*)(ws + off); off += (size_t)64 * 64 * 64 * 4;       // [bh][nt64][d]
    short* kvT_bf = (short*)(ws + off); off += (size_t)64 * 4096 * 2;          // [bh][e][d] bf16
    float* ksum_g = (float*)(ws + off); off += (size_t)64 * 64 * 4;            // [bh][d]

    if (ws_size < off) return;

    k_pre<<<768, 256, 0, stream>>>(x, w_qkv, w_out, mu, rstd, wq_bf, wo_bf);
    k_gnqkv<<<dim3(32, 16), 256, 0, stream>>>(x, gamma, beta, mu, rstd, wq_bf, b_qkv, q_t, kvp_bf, ksp);
    k_kv_reduce<<<dim3(8, 64), 256, 0, stream>>>(kvp_bf, ksp, kvT_bf, ksum_g);
    k_attn_out<<<dim3(32, 16), 256, 0, stream>>>(q_t, kvT_bf, ksum_g, wo_bf, b_out, x, out);
}

// Round 3
// 278.451 us; speedup vs baseline: 1.1056x; 1.1056x over previous
//
#include <hip/hip_runtime.h>
#include <stdint.h>

#define BATCH 16
#define CH    256
#define NSP   4096   // 64*64 spatial
#define NH    4
#define HD    64

typedef __attribute__((ext_vector_type(8))) short bf16x8;
typedef __attribute__((ext_vector_type(4))) float f32x4;
typedef __attribute__((ext_vector_type(4))) unsigned int u32x4;

__device__ __forceinline__ short f2bf(float f) {
    union { float f; unsigned u; } v; v.f = f;
    unsigned r = (v.u + 0x7fffu + ((v.u >> 16) & 1u)) >> 16;
    return (short)r;
}
__device__ __forceinline__ float bf2f(short s) {
    union { float f; unsigned u; } v; v.u = ((unsigned)(unsigned short)s) << 16;
    return v.f;
}

// ---------------- fused: GN stats (blocks 0..511) + weight bf16 convert (512..767) ----------------
__global__ __launch_bounds__(256) void k_pre(
        const float* __restrict__ x, const float* __restrict__ wq, const float* __restrict__ wo,
        float* __restrict__ mu, float* __restrict__ rstd,
        short* __restrict__ wq_bf, short* __restrict__ wo_bf) {
    int bg = blockIdx.x;
    if (bg < 512) {
        const float4* p = (const float4*)(x + (size_t)bg * 32768);
        float s = 0.f, sq = 0.f;
        for (int i = threadIdx.x; i < 8192; i += 256) {
            float4 v = p[i];
            s  += v.x + v.y + v.z + v.w;
            sq += v.x * v.x + v.y * v.y + v.z * v.z + v.w * v.w;
        }
        for (int off = 32; off; off >>= 1) { s += __shfl_down(s, off); sq += __shfl_down(sq, off); }
        __shared__ float ls[4], lq[4];
        int w = threadIdx.x >> 6;
        if ((threadIdx.x & 63) == 0) { ls[w] = s; lq[w] = sq; }
        __syncthreads();
        if (threadIdx.x == 0) {
            float S = ls[0] + ls[1] + ls[2] + ls[3];
            float Q = lq[0] + lq[1] + lq[2] + lq[3];
            float m = S / 32768.f;
            float var = Q / 32768.f - m * m;
            mu[bg] = m; rstd[bg] = rsqrtf(var + 1e-5f);
        }
    } else {
        int idx = ((bg - 512) * 256 + threadIdx.x) * 4;
        float4 v;
        short* dst;
        if (idx < 196608) { v = *(const float4*)(wq + idx); dst = wq_bf + idx; }
        else              { v = *(const float4*)(wo + (idx - 196608)); dst = wo_bf + (idx - 196608); }
        unsigned p0 = ((unsigned)(unsigned short)f2bf(v.x)) | (((unsigned)(unsigned short)f2bf(v.y)) << 16);
        unsigned p1 = ((unsigned)(unsigned short)f2bf(v.z)) | (((unsigned)(unsigned short)f2bf(v.w)) << 16);
        uint2 pk; pk.x = p0; pk.y = p1;
        *(uint2*)dst = pk;
    }
}

// ---------------- fused GN-apply + QKV + kv^T/ksum partials + q_t ----------------
// Round-0 structure: grid (64,16), 1 n-tile per block (1024 blocks = 4/CU demand,
// 3 resident by LDS -> max parallelism for this latency-bound kernel).
// ONLY change vs Round 0: A-fragments (weights) prefetched 8-deep into registers
// before each MFMA loop -> one exposed L2 latency per pass instead of ~8.
__global__ __launch_bounds__(256) void k_gnqkv(
        const float* __restrict__ x, const float* __restrict__ gamma, const float* __restrict__ beta,
        const float* __restrict__ mu, const float* __restrict__ rstd,
        const short* __restrict__ wq_bf, const float* __restrict__ b_qkv,
        short* __restrict__ q_t, short* __restrict__ kvp_bf, float* __restrict__ ksp) {
    int b = blockIdx.y, nt = blockIdx.x;
    int n0 = nt * 64;
    __shared__ short Blds[64 * 264];          // [n][c^swz]
    __shared__ union UR {
        struct { short kst[64 * 72]; short vst[64 * 72]; } s;
        short cst[64 * 136];
    } R;
    int t = threadIdx.x, lane = t & 63, wv = t >> 6, lr = lane & 15, quad = lane >> 4;

    // ---- build B tile with GN ----
    {
        const float* xb = x + (size_t)b * CH * NSP;
        int m = t & 15, cq = t >> 4;
        #pragma unroll 4
        for (int cb = 0; cb < 16; cb++) {
            int c = cb * 16 + cq;
            int g = c >> 3;
            float sc = rstd[b * 32 + g] * gamma[c];
            float sh = beta[c] - mu[b * 32 + g] * sc;
            float4 v = *(const float4*)(xb + (size_t)c * NSP + n0 + m * 4);
            float vv[4] = {v.x, v.y, v.z, v.w};
            #pragma unroll
            for (int j = 0; j < 4; j++) {
                int n = m * 4 + j;
                int cc = c ^ (((n >> 4) & 3) << 3);
                Blds[n * 264 + cc] = f2bf(vv[j] * sc + sh);
            }
        }
    }
    __syncthreads();

    // ---- per-head k/v + kv partial ----
    for (int h = 0; h < 4; h++) {
        int br0 = (wv < 2 ? 256 : 512) + h * 64;   // k rows waves 0-1, v rows waves 2-3
        int sub = (wv & 1) * 32;
        const short* wr = wq_bf + (size_t)(br0 + sub + lr) * 256 + quad * 8;
        bf16x8 A0[8], A1[8];                        // 8-deep A prefetch (16 loads issue back-to-back)
        #pragma unroll
        for (int kk = 0; kk < 8; kk++) {
            A0[kk] = *(const bf16x8*)(wr + kk * 32);
            A1[kk] = *(const bf16x8*)(wr + 16 * 256 + kk * 32);
        }
        f32x4 acc[2][4] = {};
        #pragma unroll
        for (int kk = 0; kk < 8; kk++) {
            bf16x8 bfr[4];
            #pragma unroll
            for (int ni = 0; ni < 4; ni++) {
                int rr = ni * 16 + lr;
                bfr[ni] = *(const bf16x8*)(Blds + rr * 264 + ((kk * 32 + quad * 8) ^ (((rr >> 4) & 3) << 3)));
            }
            #pragma unroll
            for (int ni = 0; ni < 4; ni++) {
                acc[0][ni] = __builtin_amdgcn_mfma_f32_16x16x32_bf16(A0[kk], bfr[ni], acc[0][ni], 0, 0, 0);
                acc[1][ni] = __builtin_amdgcn_mfma_f32_16x16x32_bf16(A1[kk], bfr[ni], acc[1][ni], 0, 0, 0);
            }
        }
        __syncthreads();   // protect R reuse from previous pass
        short* dst = (wv < 2) ? R.s.kst : R.s.vst;
        bool is_k = (wv < 2);
        #pragma unroll
        for (int mi = 0; mi < 2; mi++)
          #pragma unroll
          for (int ni = 0; ni < 4; ni++)
            #pragma unroll
            for (int r = 0; r < 4; r++) {
                int ol = sub + mi * 16 + quad * 4 + r;   // 0..63
                int nl = ni * 16 + lr;
                float v = acc[mi][ni][r] + b_qkv[br0 + ol];
                if (is_k) v = v > 0.f ? v + 1.f : __expf(v);   // elu(k)+1
                dst[ol * 72 + nl] = f2bf(v);
            }
        __syncthreads();
        // ksum partial
        {
            int d = t >> 2, nq = (t & 3) * 16;
            float s = 0.f;
            #pragma unroll
            for (int j = 0; j < 16; j++) s += bf2f(R.s.kst[d * 72 + nq + j]);
            s += __shfl_down(s, 2);
            s += __shfl_down(s, 1);
            if ((t & 3) == 0) ksp[((size_t)(b * 4 + h) * 64 + nt) * 64 + d] = s;
        }
        // kv^T partial: A = vst (e rows), B = kst (d rows), K = 64 n
        f32x4 acc2[4] = {};
        #pragma unroll
        for (int kk = 0; kk < 64; kk += 32) {
            bf16x8 af = *(const bf16x8*)(R.s.vst + (wv * 16 + lr) * 72 + kk + quad * 8);
            bf16x8 bfk[4];
            #pragma unroll
            for (int ni = 0; ni < 4; ni++)
                bfk[ni] = *(const bf16x8*)(R.s.kst + (ni * 16 + lr) * 72 + kk + quad * 8);
            #pragma unroll
            for (int ni = 0; ni < 4; ni++)
                acc2[ni] = __builtin_amdgcn_mfma_f32_16x16x32_bf16(af, bfk[ni], acc2[ni], 0, 0, 0);
        }
        short* kvdst = kvp_bf + ((size_t)(b * 4 + h) * 64 + nt) * 4096;
        #pragma unroll
        for (int ni = 0; ni < 4; ni++)
            #pragma unroll
            for (int r = 0; r < 4; r++)
                kvdst[(wv * 16 + quad * 4 + r) * 64 + ni * 16 + lr] = f2bf(acc2[ni][r]);
    }

    // ---- q passes (128 rows each), A prefetched 8-deep ----
    for (int mtq = 0; mtq < 2; mtq++) {
        int wm = wv * 32;
        const short* wr = wq_bf + (size_t)(mtq * 128 + wm + lr) * 256 + quad * 8;
        bf16x8 A0[8], A1[8];
        #pragma unroll
        for (int kk = 0; kk < 8; kk++) {
            A0[kk] = *(const bf16x8*)(wr + kk * 32);
            A1[kk] = *(const bf16x8*)(wr + 16 * 256 + kk * 32);
        }
        f32x4 acc[2][4] = {};
        #pragma unroll
        for (int kk = 0; kk < 8; kk++) {
            bf16x8 bfr[4];
            #pragma unroll
            for (int ni = 0; ni < 4; ni++) {
                int rr = ni * 16 + lr;
                bfr[ni] = *(const bf16x8*)(Blds + rr * 264 + ((kk * 32 + quad * 8) ^ (((rr >> 4) & 3) << 3)));
            }
            #pragma unroll
            for (int ni = 0; ni < 4; ni++) {
                acc[0][ni] = __builtin_amdgcn_mfma_f32_16x16x32_bf16(A0[kk], bfr[ni], acc[0][ni], 0, 0, 0);
                acc[1][ni] = __builtin_amdgcn_mfma_f32_16x16x32_bf16(A1[kk], bfr[ni], acc[1][ni], 0, 0, 0);
            }
        }
        __syncthreads();   // protect cst reuse
        #pragma unroll
        for (int mi = 0; mi < 2; mi++)
          #pragma unroll
          for (int ni = 0; ni < 4; ni++)
            #pragma unroll
            for (int r = 0; r < 4; r++) {
                int ol = wm + mi * 16 + quad * 4 + r;    // 0..127
                int nl = ni * 16 + lr;
                float v = acc[mi][ni][r] + b_qkv[mtq * 128 + ol];
                v = v > 0.f ? v + 1.f : __expf(v);       // elu(q)+1
                R.cst[nl * 136 + ol] = f2bf(v);
            }
        __syncthreads();
        #pragma unroll
        for (int i = 0; i < 4; i++) {
            int ch = t + i * 256;
            int row = ch >> 4, o8 = (ch & 15) * 8;
            int hh = mtq * 2 + (o8 >> 6), d0 = o8 & 63;
            *(u32x4*)(q_t + ((size_t)(b * 4 + hh) * NSP + n0 + row) * HD + d0) =
                *(const u32x4*)(R.cst + row * 136 + o8);
        }
    }
}

// ---------------- reduce bf16 kv partials -> bf16 kvT; fp32 ksum ----------------
// Grid (8,64) = 512 blocks. Each block: 64 chunks, 4 wave-groups each reduce 16 of
// the 64 n-tile partials, LDS combine.
__global__ __launch_bounds__(256) void k_kv_reduce(
        const short* __restrict__ kvp_bf, const float* __restrict__ ksp,
        short* __restrict__ kvT_bf, float* __restrict__ ksum_g) {
    int p = blockIdx.x, bh = blockIdx.y;
    int t = threadIdx.x, lane = t & 63, grp = t >> 6;
    int chunk = p * 64 + lane;                 // 0..511, 8 elems each
    const short* base = kvp_bf + (size_t)bh * 64 * 4096 + chunk * 8;
    float s[8] = {};
    for (int ntc = grp * 16; ntc < grp * 16 + 16; ntc++) {
        bf16x8 v = *(const bf16x8*)(base + (size_t)ntc * 4096);
        #pragma unroll
        for (int j = 0; j < 8; j++) s[j] += bf2f(v[j]);
    }
    __shared__ float red[4][64][8];
    if (grp) {
        #pragma unroll
        for (int j = 0; j < 8; j++) red[grp][lane][j] = s[j];
    }
    __syncthreads();
    if (grp == 0) {
        bf16x8 rv;
        #pragma unroll
        for (int j = 0; j < 8; j++) {
            float v = s[j] + red[1][lane][j] + red[2][lane][j] + red[3][lane][j];
            rv[j] = f2bf(v);
        }
        *(bf16x8*)(kvT_bf + (size_t)bh * 4096 + chunk * 8) = rv;
    }
    if (p == 0) {   // block-uniform branch
        const float* kb = ksp + (size_t)bh * 64 * 64 + lane;
        float ss = 0.f;
        for (int ntc = grp * 16; ntc < grp * 16 + 16; ntc++) ss += kb[(size_t)ntc * 64];
        __syncthreads();
        red[grp][lane][0] = ss;
        __syncthreads();
        if (grp == 0) ksum_g[bh * 64 + lane] = ss + red[1][lane][0] + red[2][lane][0] + red[3][lane][0];
    }
}

// ---------------- fused attention + out-projection + residual ----------------
// Round-0 structure restored: grid (64,16), LDS staging of ql/kvl (coalesced 16B/lane).
// Changes vs Round 0: (a) denominator computed by ALL 256 threads (4-way d-split
// partials in LDS, combined per-thread at the Battn write) -- removes the t<64
// 64-iteration serial loop AND one barrier per head (2 barriers/head, was 3);
// (b) wo A-fragments prefetched 8-deep in the out GEMM.
__global__ __launch_bounds__(256) void k_attn_out(
        const short* __restrict__ q_t, const short* __restrict__ kvT_bf,
        const float* __restrict__ ksum_g, const short* __restrict__ wo_bf,
        const float* __restrict__ b_out, const float* __restrict__ x,
        float* __restrict__ out) {
    int b = blockIdx.y, nt = blockIdx.x;
    int n0 = nt * 64;
    __shared__ short Battn[64 * 264];
    __shared__ short ql[64 * 72];
    __shared__ short kvl[64 * 72];
    __shared__ float dnp[4][64];
    int t = threadIdx.x, lane = t & 63, wv = t >> 6, lr = lane & 15, quad = lane >> 4;

    for (int h = 0; h < 4; h++) {
        int bh = b * 4 + h;
        #pragma unroll
        for (int i = 0; i < 2; i++) {
            int ch = t + i * 256;
            int row = ch >> 3, dc = (ch & 7) * 8;
            *(u32x4*)(ql + row * 72 + dc) =
                *(const u32x4*)(q_t + ((size_t)bh * NSP + n0 + row) * HD + dc);
            *(u32x4*)(kvl + row * 72 + dc) =
                *(const u32x4*)(kvT_bf + (size_t)bh * 4096 + row * 64 + dc);
        }
        __syncthreads();
        // denom partials: thread (n = t&63, d-range = (t>>6)*16), fully parallel
        {
            int n = t & 63, q0 = wv * 16;
            const float* ks = ksum_g + bh * 64 + q0;
            float s = 0.f;
            #pragma unroll
            for (int j = 0; j < 16; j += 8) {
                bf16x8 qv = *(const bf16x8*)(ql + n * 72 + q0 + j);
                #pragma unroll
                for (int u = 0; u < 8; u++) s += bf2f(qv[u]) * ks[j + u];
            }
            dnp[wv][n] = s;
        }
        // attention MFMA (independent of dnp; reads ql/kvl)
        f32x4 acc[4] = {};
        #pragma unroll
        for (int kk = 0; kk < 64; kk += 32) {
            bf16x8 af = *(const bf16x8*)(ql + (wv * 16 + lr) * 72 + kk + quad * 8);
            bf16x8 bfr[4];
            #pragma unroll
            for (int ni = 0; ni < 4; ni++)
                bfr[ni] = *(const bf16x8*)(kvl + (ni * 16 + lr) * 72 + kk + quad * 8);
            #pragma unroll
            for (int ni = 0; ni < 4; ni++)
                acc[ni] = __builtin_amdgcn_mfma_f32_16x16x32_bf16(af, bfr[ni], acc[ni], 0, 0, 0);
        }
        __syncthreads();   // dnp ready; ql/kvl reads complete
        float dn[4];
        #pragma unroll
        for (int r = 0; r < 4; r++) {
            int n = wv * 16 + quad * 4 + r;
            dn[r] = 1.f / (dnp[0][n] + dnp[1][n] + dnp[2][n] + dnp[3][n] + 1e-6f);
        }
        #pragma unroll
        for (int ni = 0; ni < 4; ni++)
            #pragma unroll
            for (int r = 0; r < 4; r++) {
                int n = wv * 16 + quad * 4 + r;
                Battn[n * 264 + h * 64 + ni * 16 + lr] = f2bf(acc[ni][r] * dn[r]);
            }
        __syncthreads();   // Battn slice done; next head may restage ql/kvl
    }

    // out GEMM: 2 passes of 128 o, A prefetched 8-deep, barrier-free K-loops
    for (int p = 0; p < 2; p++) {
        int rbase = p * 128 + wv * 32;
        const short* wr = wo_bf + (size_t)(rbase + lr) * 256 + quad * 8;
        bf16x8 A0[8], A1[8];
        #pragma unroll
        for (int kk = 0; kk < 8; kk++) {
            A0[kk] = *(const bf16x8*)(wr + kk * 32);
            A1[kk] = *(const bf16x8*)(wr + 16 * 256 + kk * 32);
        }
        f32x4 acc[2][4] = {};
        #pragma unroll
        for (int kk = 0; kk < 8; kk++) {
            bf16x8 bfr[4];
            #pragma unroll
            for (int ni = 0; ni < 4; ni++)
                bfr[ni] = *(const bf16x8*)(Battn + (ni * 16 + lr) * 264 + kk * 32 + quad * 8);
            #pragma unroll
            for (int ni = 0; ni < 4; ni++) {
                acc[0][ni] = __builtin_amdgcn_mfma_f32_16x16x32_bf16(A0[kk], bfr[ni], acc[0][ni], 0, 0, 0);
                acc[1][ni] = __builtin_amdgcn_mfma_f32_16x16x32_bf16(A1[kk], bfr[ni], acc[1][ni], 0, 0, 0);
            }
        }
        #pragma unroll
        for (int mi = 0; mi < 2; mi++)
          #pragma unroll
          for (int ni = 0; ni < 4; ni++)
            #pragma unroll
            for (int r = 0; r < 4; r++) {
                int o = rbase + mi * 16 + quad * 4 + r;
                int nl = ni * 16 + lr;
                size_t idx = ((size_t)b * CH + o) * NSP + n0 + nl;
                out[idx] = acc[mi][ni][r] + b_out[o] + x[idx];
            }
    }
}

extern "C" void kernel_launch(void* const* d_in, const int* in_sizes, int n_in,
                              void* d_out, int out_size, void* d_ws, size_t ws_size,
                              hipStream_t stream) {
    const float* x     = (const float*)d_in[0];
    const float* gamma = (const float*)d_in[1];
    const float* beta  = (const float*)d_in[2];
    const float* w_qkv = (const float*)d_in[3];
    const float* b_qkv = (const float*)d_in[4];
    const float* w_out = (const float*)d_in[5];
    const float* b_out = (const float*)d_in[6];
    float* out = (float*)d_out;

    char* ws = (char*)d_ws;
    size_t off = 0;
    float* mu     = (float*)(ws + off); off += 2048;
    float* rstd   = (float*)(ws + off); off += 2048;
    short* wq_bf  = (short*)(ws + off); off += (size_t)768 * 256 * 2;
    short* wo_bf  = (short*)(ws + off); off += (size_t)256 * 256 * 2;
    short* q_t    = (short*)(ws + off); off += (size_t)BATCH * NSP * CH * 2;   // [b][h][n][d]
    short* kvp_bf = (short*)(ws + off); off += (size_t)64 * 64 * 4096 * 2;     // [bh][nt64][e][d] bf16
    float* ksp    = (float*)(ws + off); off += (size_t)64 * 64 * 64 * 4;       // [bh][nt64][d]
    short* kvT_bf = (short*)(ws + off); off += (size_t)64 * 4096 * 2;          // [bh][e][d] bf16
    float* ksum_g = (float*)(ws + off); off += (size_t)64 * 64 * 4;            // [bh][d]

    if (ws_size < off) return;

    k_pre<<<768, 256, 0, stream>>>(x, w_qkv, w_out, mu, rstd, wq_bf, wo_bf);
    k_gnqkv<<<dim3(64, 16), 256, 0, stream>>>(x, gamma, beta, mu, rstd, wq_bf, b_qkv, q_t, kvp_bf, ksp);
    k_kv_reduce<<<dim3(8, 64), 256, 0, stream>>>(kvp_bf, ksp, kvT_bf, ksum_g);
    k_attn_out<<<dim3(64, 16), 256, 0, stream>>>(q_t, kvT_bf, ksum_g, wo_bf, b_out, x, out);
}

// Round 4
// 271.949 us; speedup vs baseline: 1.1320x; 1.0239x over previous
//
#include <hip/hip_runtime.h>
#include <stdint.h>

#define BATCH 16
#define CH    256
#define NSP   4096   // 64*64 spatial
#define NH    4
#define HD    64

typedef __attribute__((ext_vector_type(8))) short bf16x8;
typedef __attribute__((ext_vector_type(4))) float f32x4;
typedef __attribute__((ext_vector_type(4))) unsigned int u32x4;

__device__ __forceinline__ short f2bf(float f) {
    union { float f; unsigned u; } v; v.f = f;
    unsigned r = (v.u + 0x7fffu + ((v.u >> 16) & 1u)) >> 16;
    return (short)r;
}
__device__ __forceinline__ float bf2f(short s) {
    union { float f; unsigned u; } v; v.u = ((unsigned)(unsigned short)s) << 16;
    return v.f;
}

// ---------------- fused: GN stats + sc/sh tables (blocks 0..511) + weight convert (512..767) ----
__global__ __launch_bounds__(256) void k_pre(
        const float* __restrict__ x, const float* __restrict__ wq, const float* __restrict__ wo,
        const float* __restrict__ gamma, const float* __restrict__ beta,
        float* __restrict__ sc_tab, float* __restrict__ sh_tab,
        short* __restrict__ wq_bf, short* __restrict__ wo_bf) {
    int bg = blockIdx.x;
    if (bg < 512) {
        const float4* p = (const float4*)(x + (size_t)bg * 32768);
        float s = 0.f, sq = 0.f;
        #pragma unroll 4
        for (int i = threadIdx.x; i < 8192; i += 256) {
            float4 v = p[i];
            s  += v.x + v.y + v.z + v.w;
            sq += v.x * v.x + v.y * v.y + v.z * v.z + v.w * v.w;
        }
        for (int off = 32; off; off >>= 1) { s += __shfl_down(s, off); sq += __shfl_down(sq, off); }
        __shared__ float ls[4], lq[4];
        int w = threadIdx.x >> 6;
        if ((threadIdx.x & 63) == 0) { ls[w] = s; lq[w] = sq; }
        __syncthreads();
        if (threadIdx.x == 0) {
            float S = ls[0] + ls[1] + ls[2] + ls[3];
            float Q = lq[0] + lq[1] + lq[2] + lq[3];
            float m = S / 32768.f;
            float var = Q / 32768.f - m * m;
            ls[0] = m; lq[0] = rsqrtf(var + 1e-5f);
        }
        __syncthreads();
        if (threadIdx.x < 8) {
            int b = bg >> 5, g = bg & 31, c = g * 8 + threadIdx.x;
            float r = lq[0], mm = ls[0];
            float sc = r * gamma[c];
            sc_tab[b * 256 + c] = sc;
            sh_tab[b * 256 + c] = beta[c] - mm * sc;
        }
    } else {
        int idx = ((bg - 512) * 256 + threadIdx.x) * 4;
        float4 v;
        short* dst;
        if (idx < 196608) { v = *(const float4*)(wq + idx); dst = wq_bf + idx; }
        else              { v = *(const float4*)(wo + (idx - 196608)); dst = wo_bf + (idx - 196608); }
        unsigned p0 = ((unsigned)(unsigned short)f2bf(v.x)) | (((unsigned)(unsigned short)f2bf(v.y)) << 16);
        unsigned p1 = ((unsigned)(unsigned short)f2bf(v.z)) | (((unsigned)(unsigned short)f2bf(v.w)) << 16);
        uint2 pk; pk.x = p0; pk.y = p1;
        *(uint2*)dst = pk;
    }
}

// ---------------- fused GN-apply + QKV + kv^T/ksum partials + q_t ----------------
// Round-0 structure (grid (64,16), indexed addressing). A-fragment prefetch is PINNED
// with sched_barrier(0): the 16 global loads cannot be sunk into the MFMA loop by the
// scheduler -> one exposed L2 latency per pass. B-build: all 16 HBM loads issued
// before any use. launch_bounds(256,3): VGPR cap ~170 keeps 3 blocks/CU (= LDS cap).
__global__ __launch_bounds__(256, 3) void k_gnqkv(
        const float* __restrict__ x,
        const float* __restrict__ sc_tab, const float* __restrict__ sh_tab,
        const short* __restrict__ wq_bf, const float* __restrict__ b_qkv,
        short* __restrict__ q_t, short* __restrict__ kvp_bf, float* __restrict__ ksp) {
    int b = blockIdx.y, nt = blockIdx.x;
    int n0 = nt * 64;
    __shared__ short Blds[64 * 264];          // [n][c^swz]
    __shared__ union UR {
        struct { short kst[64 * 72]; short vst[64 * 72]; } s;
        short cst[64 * 136];
    } R;
    int t = threadIdx.x, lane = t & 63, wv = t >> 6, lr = lane & 15, quad = lane >> 4;

    // ---- build B tile with GN: issue all 16 HBM loads first, then convert ----
    {
        const float* xb = x + (size_t)b * CH * NSP + n0;
        const float* scb = sc_tab + b * 256;
        const float* shb = sh_tab + b * 256;
        int m = t & 15, cq = t >> 4;
        float4 vv[16];
        float scA[16], shA[16];
        #pragma unroll
        for (int cb = 0; cb < 16; cb++) {
            int c = cb * 16 + cq;
            vv[cb] = *(const float4*)(xb + (size_t)c * NSP + m * 4);
            scA[cb] = scb[c]; shA[cb] = shb[c];
        }
        #pragma unroll
        for (int cb = 0; cb < 16; cb++) {
            int c = cb * 16 + cq;
            float va[4] = {vv[cb].x, vv[cb].y, vv[cb].z, vv[cb].w};
            #pragma unroll
            for (int j = 0; j < 4; j++) {
                int n = m * 4 + j;
                int cc = c ^ (((n >> 4) & 3) << 3);
                Blds[n * 264 + cc] = f2bf(va[j] * scA[cb] + shA[cb]);
            }
        }
    }
    __syncthreads();

    // ---- per-head k/v + kv partial ----
    #pragma unroll 1
    for (int h = 0; h < 4; h++) {
        int br0 = (wv < 2 ? 256 : 512) + h * 64;   // k rows waves 0-1, v rows waves 2-3
        int sub = (wv & 1) * 32;
        bf16x8 A0[8], A1[8];
        #pragma unroll
        for (int kk = 0; kk < 8; kk++) {
            A0[kk] = *(const bf16x8*)(wq_bf + (size_t)(br0 + sub + lr) * 256 + kk * 32 + quad * 8);
            A1[kk] = *(const bf16x8*)(wq_bf + (size_t)(br0 + sub + 16 + lr) * 256 + kk * 32 + quad * 8);
        }
        __builtin_amdgcn_sched_barrier(0);   // loads may NOT sink below this point
        f32x4 acc[2][4] = {};
        #pragma unroll
        for (int kk = 0; kk < 8; kk++) {
            bf16x8 bfr[4];
            #pragma unroll
            for (int ni = 0; ni < 4; ni++) {
                int rr = ni * 16 + lr;
                bfr[ni] = *(const bf16x8*)(Blds + rr * 264 + ((kk * 32 + quad * 8) ^ (((rr >> 4) & 3) << 3)));
            }
            #pragma unroll
            for (int ni = 0; ni < 4; ni++) {
                acc[0][ni] = __builtin_amdgcn_mfma_f32_16x16x32_bf16(A0[kk], bfr[ni], acc[0][ni], 0, 0, 0);
                acc[1][ni] = __builtin_amdgcn_mfma_f32_16x16x32_bf16(A1[kk], bfr[ni], acc[1][ni], 0, 0, 0);
            }
        }
        __syncthreads();   // protect R reuse from previous pass
        short* dst = (wv < 2) ? R.s.kst : R.s.vst;
        bool is_k = (wv < 2);
        #pragma unroll
        for (int mi = 0; mi < 2; mi++)
          #pragma unroll
          for (int ni = 0; ni < 4; ni++)
            #pragma unroll
            for (int r = 0; r < 4; r++) {
                int ol = sub + mi * 16 + quad * 4 + r;   // 0..63
                int nl = ni * 16 + lr;
                float v = acc[mi][ni][r] + b_qkv[br0 + ol];
                if (is_k) v = v > 0.f ? v + 1.f : __expf(v);   // elu(k)+1
                dst[ol * 72 + nl] = f2bf(v);
            }
        __syncthreads();
        // ksum partial
        {
            int d = t >> 2, nq = (t & 3) * 16;
            float s = 0.f;
            #pragma unroll
            for (int j = 0; j < 16; j++) s += bf2f(R.s.kst[d * 72 + nq + j]);
            s += __shfl_down(s, 2);
            s += __shfl_down(s, 1);
            if ((t & 3) == 0) ksp[((size_t)(b * 4 + h) * 64 + nt) * 64 + d] = s;
        }
        // kv^T partial: A = vst (e rows), B = kst (d rows), K = 64 n
        f32x4 acc2[4] = {};
        #pragma unroll
        for (int kk = 0; kk < 64; kk += 32) {
            bf16x8 af = *(const bf16x8*)(R.s.vst + (wv * 16 + lr) * 72 + kk + quad * 8);
            bf16x8 bfk[4];
            #pragma unroll
            for (int ni = 0; ni < 4; ni++)
                bfk[ni] = *(const bf16x8*)(R.s.kst + (ni * 16 + lr) * 72 + kk + quad * 8);
            #pragma unroll
            for (int ni = 0; ni < 4; ni++)
                acc2[ni] = __builtin_amdgcn_mfma_f32_16x16x32_bf16(af, bfk[ni], acc2[ni], 0, 0, 0);
        }
        short* kvdst = kvp_bf + ((size_t)(b * 4 + h) * 64 + nt) * 4096;
        #pragma unroll
        for (int ni = 0; ni < 4; ni++)
            #pragma unroll
            for (int r = 0; r < 4; r++)
                kvdst[(wv * 16 + quad * 4 + r) * 64 + ni * 16 + lr] = f2bf(acc2[ni][r]);
    }

    // ---- q passes (128 rows each), pinned A-prefetch ----
    #pragma unroll 1
    for (int mtq = 0; mtq < 2; mtq++) {
        int wm = wv * 32;
        bf16x8 A0[8], A1[8];
        #pragma unroll
        for (int kk = 0; kk < 8; kk++) {
            A0[kk] = *(const bf16x8*)(wq_bf + (size_t)(mtq * 128 + wm + lr) * 256 + kk * 32 + quad * 8);
            A1[kk] = *(const bf16x8*)(wq_bf + (size_t)(mtq * 128 + wm + 16 + lr) * 256 + kk * 32 + quad * 8);
        }
        __builtin_amdgcn_sched_barrier(0);
        f32x4 acc[2][4] = {};
        #pragma unroll
        for (int kk = 0; kk < 8; kk++) {
            bf16x8 bfr[4];
            #pragma unroll
            for (int ni = 0; ni < 4; ni++) {
                int rr = ni * 16 + lr;
                bfr[ni] = *(const bf16x8*)(Blds + rr * 264 + ((kk * 32 + quad * 8) ^ (((rr >> 4) & 3) << 3)));
            }
            #pragma unroll
            for (int ni = 0; ni < 4; ni++) {
                acc[0][ni] = __builtin_amdgcn_mfma_f32_16x16x32_bf16(A0[kk], bfr[ni], acc[0][ni], 0, 0, 0);
                acc[1][ni] = __builtin_amdgcn_mfma_f32_16x16x32_bf16(A1[kk], bfr[ni], acc[1][ni], 0, 0, 0);
            }
        }
        __syncthreads();   // protect cst reuse
        #pragma unroll
        for (int mi = 0; mi < 2; mi++)
          #pragma unroll
          for (int ni = 0; ni < 4; ni++)
            #pragma unroll
            for (int r = 0; r < 4; r++) {
                int ol = wm + mi * 16 + quad * 4 + r;    // 0..127
                int nl = ni * 16 + lr;
                float v = acc[mi][ni][r] + b_qkv[mtq * 128 + ol];
                v = v > 0.f ? v + 1.f : __expf(v);       // elu(q)+1
                R.cst[nl * 136 + ol] = f2bf(v);
            }
        __syncthreads();
        #pragma unroll
        for (int i = 0; i < 4; i++) {
            int ch = t + i * 256;
            int row = ch >> 4, o8 = (ch & 15) * 8;
            int hh = mtq * 2 + (o8 >> 6), d0 = o8 & 63;
            *(u32x4*)(q_t + ((size_t)(b * 4 + hh) * NSP + n0 + row) * HD + d0) =
                *(const u32x4*)(R.cst + row * 136 + o8);
        }
    }
}

// ---------------- reduce bf16 kv partials -> bf16 kvT; fp32 ksum ----------------
__global__ __launch_bounds__(256) void k_kv_reduce(
        const short* __restrict__ kvp_bf, const float* __restrict__ ksp,
        short* __restrict__ kvT_bf, float* __restrict__ ksum_g) {
    int p = blockIdx.x, bh = blockIdx.y;
    int t = threadIdx.x, lane = t & 63, grp = t >> 6;
    int chunk = p * 64 + lane;                 // 0..511, 8 elems each
    const short* base = kvp_bf + (size_t)bh * 64 * 4096 + chunk * 8;
    float s[8] = {};
    for (int ntc = grp * 16; ntc < grp * 16 + 16; ntc++) {
        bf16x8 v = *(const bf16x8*)(base + (size_t)ntc * 4096);
        #pragma unroll
        for (int j = 0; j < 8; j++) s[j] += bf2f(v[j]);
    }
    __shared__ float red[4][64][8];
    if (grp) {
        #pragma unroll
        for (int j = 0; j < 8; j++) red[grp][lane][j] = s[j];
    }
    __syncthreads();
    if (grp == 0) {
        bf16x8 rv;
        #pragma unroll
        for (int j = 0; j < 8; j++) {
            float v = s[j] + red[1][lane][j] + red[2][lane][j] + red[3][lane][j];
            rv[j] = f2bf(v);
        }
        *(bf16x8*)(kvT_bf + (size_t)bh * 4096 + chunk * 8) = rv;
    }
    if (p == 0) {   // block-uniform branch
        const float* kb = ksp + (size_t)bh * 64 * 64 + lane;
        float ss = 0.f;
        for (int ntc = grp * 16; ntc < grp * 16 + 16; ntc++) ss += kb[(size_t)ntc * 64];
        __syncthreads();
        red[grp][lane][0] = ss;
        __syncthreads();
        if (grp == 0) ksum_g[bh * 64 + lane] = ss + red[1][lane][0] + red[2][lane][0] + red[3][lane][0];
    }
}

// ---------------- fused attention + out-projection + residual ----------------
// Round-3 structure + occupancy fix: unroll-1 head loop (stops liveness-merge that
// produced VGPR 228 -> 2 blocks/CU), pinned A-prefetch in out GEMM,
// launch_bounds(256,3) -> 3 blocks/CU (matches LDS cap).
__global__ __launch_bounds__(256, 3) void k_attn_out(
        const short* __restrict__ q_t, const short* __restrict__ kvT_bf,
        const float* __restrict__ ksum_g, const short* __restrict__ wo_bf,
        const float* __restrict__ b_out, const float* __restrict__ x,
        float* __restrict__ out) {
    int b = blockIdx.y, nt = blockIdx.x;
    int n0 = nt * 64;
    __shared__ short Battn[64 * 264];
    __shared__ short ql[64 * 72];
    __shared__ short kvl[64 * 72];
    __shared__ float dnp[4][64];
    int t = threadIdx.x, lane = t & 63, wv = t >> 6, lr = lane & 15, quad = lane >> 4;

    #pragma unroll 1
    for (int h = 0; h < 4; h++) {
        int bh = b * 4 + h;
        #pragma unroll
        for (int i = 0; i < 2; i++) {
            int ch = t + i * 256;
            int row = ch >> 3, dc = (ch & 7) * 8;
            *(u32x4*)(ql + row * 72 + dc) =
                *(const u32x4*)(q_t + ((size_t)bh * NSP + n0 + row) * HD + dc);
            *(u32x4*)(kvl + row * 72 + dc) =
                *(const u32x4*)(kvT_bf + (size_t)bh * 4096 + row * 64 + dc);
        }
        __syncthreads();
        // denom partials: thread (n = t&63, d-range = (t>>6)*16), fully parallel
        {
            int n = t & 63, q0 = wv * 16;
            const float* ks = ksum_g + bh * 64 + q0;
            float s = 0.f;
            #pragma unroll
            for (int j = 0; j < 16; j += 8) {
                bf16x8 qv = *(const bf16x8*)(ql + n * 72 + q0 + j);
                #pragma unroll
                for (int u = 0; u < 8; u++) s += bf2f(qv[u]) * ks[j + u];
            }
            dnp[wv][n] = s;
        }
        // attention MFMA (independent of dnp; reads ql/kvl)
        f32x4 acc[4] = {};
        #pragma unroll
        for (int kk = 0; kk < 64; kk += 32) {
            bf16x8 af = *(const bf16x8*)(ql + (wv * 16 + lr) * 72 + kk + quad * 8);
            bf16x8 bfr[4];
            #pragma unroll
            for (int ni = 0; ni < 4; ni++)
                bfr[ni] = *(const bf16x8*)(kvl + (ni * 16 + lr) * 72 + kk + quad * 8);
            #pragma unroll
            for (int ni = 0; ni < 4; ni++)
                acc[ni] = __builtin_amdgcn_mfma_f32_16x16x32_bf16(af, bfr[ni], acc[ni], 0, 0, 0);
        }
        __syncthreads();   // dnp ready; ql/kvl reads complete
        float dn[4];
        #pragma unroll
        for (int r = 0; r < 4; r++) {
            int n = wv * 16 + quad * 4 + r;
            dn[r] = 1.f / (dnp[0][n] + dnp[1][n] + dnp[2][n] + dnp[3][n] + 1e-6f);
        }
        #pragma unroll
        for (int ni = 0; ni < 4; ni++)
            #pragma unroll
            for (int r = 0; r < 4; r++) {
                int n = wv * 16 + quad * 4 + r;
                Battn[n * 264 + h * 64 + ni * 16 + lr] = f2bf(acc[ni][r] * dn[r]);
            }
        __syncthreads();   // Battn slice done; next head may restage ql/kvl
    }

    // out GEMM: 2 passes of 128 o, pinned 8-deep A-prefetch, barrier-free K-loops
    #pragma unroll 1
    for (int p = 0; p < 2; p++) {
        int rbase = p * 128 + wv * 32;
        bf16x8 A0[8], A1[8];
        #pragma unroll
        for (int kk = 0; kk < 8; kk++) {
            A0[kk] = *(const bf16x8*)(wo_bf + (size_t)(rbase + lr) * 256 + kk * 32 + quad * 8);
            A1[kk] = *(const bf16x8*)(wo_bf + (size_t)(rbase + 16 + lr) * 256 + kk * 32 + quad * 8);
        }
        __builtin_amdgcn_sched_barrier(0);
        f32x4 acc[2][4] = {};
        #pragma unroll
        for (int kk = 0; kk < 8; kk++) {
            bf16x8 bfr[4];
            #pragma unroll
            for (int ni = 0; ni < 4; ni++)
                bfr[ni] = *(const bf16x8*)(Battn + (ni * 16 + lr) * 264 + kk * 32 + quad * 8);
            #pragma unroll
            for (int ni = 0; ni < 4; ni++) {
                acc[0][ni] = __builtin_amdgcn_mfma_f32_16x16x32_bf16(A0[kk], bfr[ni], acc[0][ni], 0, 0, 0);
                acc[1][ni] = __builtin_amdgcn_mfma_f32_16x16x32_bf16(A1[kk], bfr[ni], acc[1][ni], 0, 0, 0);
            }
        }
        #pragma unroll
        for (int mi = 0; mi < 2; mi++)
          #pragma unroll
          for (int ni = 0; ni < 4; ni++)
            #pragma unroll
            for (int r = 0; r < 4; r++) {
                int o = rbase + mi * 16 + quad * 4 + r;
                int nl = ni * 16 + lr;
                size_t idx = ((size_t)b * CH + o) * NSP + n0 + nl;
                out[idx] = acc[mi][ni][r] + b_out[o] + x[idx];
            }
    }
}

extern "C" void kernel_launch(void* const* d_in, const int* in_sizes, int n_in,
                              void* d_out, int out_size, void* d_ws, size_t ws_size,
                              hipStream_t stream) {
    const float* x     = (const float*)d_in[0];
    const float* gamma = (const float*)d_in[1];
    const float* beta  = (const float*)d_in[2];
    const float* w_qkv = (const float*)d_in[3];
    const float* b_qkv = (const float*)d_in[4];
    const float* w_out = (const float*)d_in[5];
    const float* b_out = (const float*)d_in[6];
    float* out = (float*)d_out;

    char* ws = (char*)d_ws;
    size_t off = 0;
    float* sc_tab = (float*)(ws + off); off += (size_t)16 * 256 * 4;
    float* sh_tab = (float*)(ws + off); off += (size_t)16 * 256 * 4;
    short* wq_bf  = (short*)(ws + off); off += (size_t)768 * 256 * 2;
    short* wo_bf  = (short*)(ws + off); off += (size_t)256 * 256 * 2;
    short* q_t    = (short*)(ws + off); off += (size_t)BATCH * NSP * CH * 2;   // [b][h][n][d]
    short* kvp_bf = (short*)(ws + off); off += (size_t)64 * 64 * 4096 * 2;     // [bh][nt64][e][d] bf16
    float* ksp    = (float*)(ws + off); off += (size_t)64 * 64 * 64 * 4;       // [bh][nt64][d]
    short* kvT_bf = (short*)(ws + off); off += (size_t)64 * 4096 * 2;          // [bh][e][d] bf16
    float* ksum_g = (float*)(ws + off); off += (size_t)64 * 64 * 4;            // [bh][d]

    if (ws_size < off) return;

    k_pre<<<768, 256, 0, stream>>>(x, w_qkv, w_out, gamma, beta, sc_tab, sh_tab, wq_bf, wo_bf);
    k_gnqkv<<<dim3(64, 16), 256, 0, stream>>>(x, sc_tab, sh_tab, wq_bf, b_qkv, q_t, kvp_bf, ksp);
    k_kv_reduce<<<dim3(2 * 4, 64), 256, 0, stream>>>(kvp_bf, ksp, kvT_bf, ksum_g);
    k_attn_out<<<dim3(64, 16), 256, 0, stream>>>(q_t, kvT_bf, ksum_g, wo_bf, b_out, x, out);
}